// Round 5
// baseline (89.701 us; speedup 1.0000x reference)
//
#include <hip/hip_runtime.h>
#include <hip/hip_bf16.h>

// ---- problem constants ----
#define TLEN   524288
#define NBATCH 16
#define KSZ    1024
#define NBINS  513
#define NCH    1026
#define NFRM   2045
#define HOP    256
#define MROWS  1024        // exact: 513 cos rows + 511 sin rows (see r3)
#define XPAD   525056
// ---- GEMM tiling (256x256, BK=64, 8 waves, 8-phase schedule) ----
#define BM 256
#define BN 256
#define BK 64
#define NT (KSZ / BK)      // 16 K-tiles
#define LDS_BYTES 131072

typedef __bf16 bf16x8 __attribute__((ext_vector_type(8)));
typedef float  f32x4  __attribute__((ext_vector_type(4)));

// ------------------------------------------------------------------
// Kernel 1: windowed Fourier basis, 1024 nonzero rows only.
// ------------------------------------------------------------------
__global__ void build_basis_k(const float* __restrict__ window,
                              __hip_bfloat16* __restrict__ basis) {
    int idx = blockIdx.x * 256 + threadIdx.x;
    if (idx >= MROWS * KSZ) return;
    int g = idx >> 10;
    int k = idx & (KSZ - 1);
    int cc = (g < NBINS) ? g : (g - 512);
    int m = (cc * k) & (KSZ - 1);
    float ang = (float)m * (6.283185307179586f / (float)KSZ);
    float s, co;
    sincosf(ang, &s, &co);
    float v = ((g < NBINS) ? co : -s) * window[k];
    basis[idx] = __float2bfloat16(v);
}

// ------------------------------------------------------------------
// Kernel 2: x fp32 -> bf16, per-batch padded to XPAD with zeros.
// ------------------------------------------------------------------
__global__ void convert_x_k(const float* __restrict__ x,
                            __hip_bfloat16* __restrict__ xb) {
    const int total4 = NBATCH * (XPAD / 4);
    for (int i = blockIdx.x * blockDim.x + threadIdx.x; i < total4;
         i += gridDim.x * blockDim.x) {
        int b = i / (XPAD / 4);
        int t = (i - b * (XPAD / 4)) * 4;
        float4 v = make_float4(0.f, 0.f, 0.f, 0.f);
        if (t < TLEN)
            v = *(const float4*)(x + (size_t)b * TLEN + t);
        ushort4 o;
        o.x = __builtin_bit_cast(unsigned short, __float2bfloat16(v.x));
        o.y = __builtin_bit_cast(unsigned short, __float2bfloat16(v.y));
        o.z = __builtin_bit_cast(unsigned short, __float2bfloat16(v.z));
        o.w = __builtin_bit_cast(unsigned short, __float2bfloat16(v.w));
        *(ushort4*)((unsigned short*)xb + (size_t)i * 4) = o;
    }
}

// ------------------------------------------------------------------
// Kernel 2b: zero channels 513 and 1025 (identically-zero basis rows).
// ------------------------------------------------------------------
__global__ void zero_rows_k(float* __restrict__ out) {
    int idx = blockIdx.x * 256 + threadIdx.x;
    if (idx >= NBATCH * 2 * NFRM) return;
    int b = idx / (2 * NFRM);
    int r = idx - b * (2 * NFRM);
    int c = (r < NFRM) ? 513 : 1025;
    int f = (r < NFRM) ? r : (r - NFRM);
    out[((size_t)b * NCH + c) * NFRM + f] = 0.0f;
}

// ------------------------------------------------------------------
// Kernel 3: 256x256 8-phase GEMM, 8 waves (2M x 4N), per-wave 128x64.
// Same verified schedule as r3/r4; this round: ALL addressing hoisted
// out of the K-loop (24 LDS offsets, odd-buffer via +32768 DS-imm;
// 8 running global src pointers, +=128B/tile), MMAC ks-outermost,
// STAGE issued before the phase's ds_reads.
// ------------------------------------------------------------------
extern __shared__ char smem[];

#define LOAD_BFR(dst, PAR)                                                  \
    { _Pragma("unroll") for (int ni = 0; ni < 4; ++ni)                      \
      _Pragma("unroll") for (int ks = 0; ks < 2; ++ks)                      \
        dst[ni][ks] = *(const bf16x8*)(Bs + (PAR) + b_off[ni][ks]); }

#define LOAD_AFRQ(q, PAR)                                                   \
    { _Pragma("unroll") for (int mi = 0; mi < 2; ++mi)                      \
      _Pragma("unroll") for (int ks = 0; ks < 2; ++ks)                      \
        afr[mi][ks] = *(const bf16x8*)(As + (PAR) + a_off[q][mi][ks]); }

#define MMACQ(q, bfr)                                                       \
    __builtin_amdgcn_s_setprio(1);                                          \
    _Pragma("unroll") for (int ks = 0; ks < 2; ++ks)                        \
    _Pragma("unroll") for (int mi = 0; mi < 2; ++mi)                        \
    _Pragma("unroll") for (int ni = 0; ni < 4; ++ni)                        \
        acc[(q) * 2 + mi][ni] = __builtin_amdgcn_mfma_f32_16x16x32_bf16(    \
            afr[mi][ks], bfr[ni][ks], acc[(q) * 2 + mi][ni], 0, 0, 0);      \
    __builtin_amdgcn_s_setprio(0);

#define BAR() __builtin_amdgcn_s_barrier()

#define STAGE_A_(H, PAR, GUARD)                                             \
    if (GUARD) { _Pragma("unroll") for (int i = 0; i < 2; ++i) {            \
        __builtin_amdgcn_global_load_lds(                                   \
            (const __attribute__((address_space(1))) void*)gA[H][i],        \
            (__attribute__((address_space(3))) void*)                       \
                (As + (PAR) + (H) * 16384 + i * 8192 + ldsl),               \
            16, 0, 0);                                                      \
        gA[H][i] += 128; } }

#define STAGE_B_(H, PAR, GUARD)                                             \
    if (GUARD) { _Pragma("unroll") for (int i = 0; i < 2; ++i) {            \
        __builtin_amdgcn_global_load_lds(                                   \
            (const __attribute__((address_space(1))) void*)gB[H][i],        \
            (__attribute__((address_space(3))) void*)                       \
                (Bs + (PAR) + (H) * 16384 + i * 8192 + ldsl),               \
            16, 0, 0);                                                      \
        gB[H][i] += 128; } }

// per-tile schedule (identical hazard structure to verified r3/r4):
// ph0: STAGE A-h1(v+1);  ph1: STAGE B-h0(v+2);  ph2: STAGE B-h1(v+2);
// ph3: STAGE A-h0(v+2), vmcnt(6) [retires {B0,B1,A0,A1}(v+1)], BFR(v+1).
#define TILE_BODY(V, PAR, NPAR, BCUR, BNEXT, DONEXT, VMTXT)                 \
    STAGE_A_(1, NPAR, (V) + 1 < NT);                                        \
    LOAD_AFRQ(0, PAR);                                                      \
    BAR(); MMACQ(0, BCUR); BAR();                                           \
    STAGE_B_(0, PAR, (V) + 2 < NT);                                         \
    LOAD_AFRQ(1, PAR);                                                      \
    BAR(); MMACQ(1, BCUR); BAR();                                           \
    STAGE_B_(1, PAR, (V) + 2 < NT);                                         \
    LOAD_AFRQ(2, PAR);                                                      \
    BAR(); MMACQ(2, BCUR); BAR();                                           \
    STAGE_A_(0, PAR, (V) + 2 < NT);                                         \
    LOAD_AFRQ(3, PAR);                                                      \
    BAR(); MMACQ(3, BCUR);                                                  \
    asm volatile("s_waitcnt " VMTXT ::: "memory");                          \
    if (DONEXT) { LOAD_BFR(BNEXT, NPAR); }                                  \
    BAR();

__launch_bounds__(512, 2)
__global__ void stft_gemm_k(const __hip_bfloat16* __restrict__ basis,
                            const __hip_bfloat16* __restrict__ xb,
                            float* __restrict__ out) {
    const int tid  = threadIdx.x;
    const int wave = tid >> 6;
    const int lane = tid & 63;
    const int l16  = lane & 15;
    const int lg   = lane >> 4;
    const int wr   = wave >> 2;          // 0..1 (M)
    const int wc   = wave & 3;           // 0..3 (N)
    const int f0   = blockIdx.x * BN;
    const int c0   = blockIdx.y * BM;
    const int bb   = blockIdx.z;
    const __hip_bfloat16* xbb = xb + (size_t)bb * XPAD;

    char* As = smem;            // 64 KiB (2 buf x 2 half x 16 KiB)
    char* Bs = smem + 65536;    // 64 KiB
    const int ldsl = wave * 1024;        // wave-uniform LDS dest slot

    // ---- hoisted LDS read offsets (even buffer; odd = +32768 imm) ----
    int a_off[4][2][2], b_off[4][2];
    #pragma unroll
    for (int q = 0; q < 4; ++q)
        #pragma unroll
        for (int mi = 0; mi < 2; ++mi)
            #pragma unroll
            for (int ks = 0; ks < 2; ++ks) {
                int j = wr * 64 + (q & 1) * 32 + mi * 16 + l16;
                a_off[q][mi][ks] =
                    (q >> 1) * 16384 + (j * 8 + ((ks * 4 + lg) ^ (j & 7))) * 16;
            }
    #pragma unroll
    for (int ni = 0; ni < 4; ++ni)
        #pragma unroll
        for (int ks = 0; ks < 2; ++ks) {
            int j = (wc & 1) * 64 + ni * 16 + l16;
            b_off[ni][ks] =
                (wc >> 1) * 16384 + (j * 8 + ((ks * 4 + lg) ^ (j & 7))) * 16;
        }

    // ---- hoisted running global source pointers (+=128B per stage) ----
    const char* gA[2][2];
    const char* gB[2][2];
    #pragma unroll
    for (int i = 0; i < 2; ++i) {
        int chunk = i * 512 + tid;
        int j   = chunk >> 3;
        int kch = (chunk & 7) ^ (j & 7);
        gA[0][i] = (const char*)(basis +
            (size_t)(c0 + (j >> 6) * 128 + (j & 63)) * KSZ + kch * 8);
        gA[1][i] = (const char*)(basis +
            (size_t)(c0 + (j >> 6) * 128 + 64 + (j & 63)) * KSZ + kch * 8);
        gB[0][i] = (const char*)(xbb + (size_t)(f0 + j) * HOP + kch * 8);
        gB[1][i] = (const char*)(xbb + (size_t)(f0 + 128 + j) * HOP + kch * 8);
    }

    f32x4 acc[8][4] = {};
    bf16x8 afr[2][2], bfrA[4][2], bfrB[4][2];

    // ---- prologue: tile 0 (4 halves) + B0,B1,A0 of tile 1 ----
    STAGE_A_(0, 0, 1); STAGE_A_(1, 0, 1); STAGE_B_(0, 0, 1); STAGE_B_(1, 0, 1);
    STAGE_B_(0, 32768, 1); STAGE_B_(1, 32768, 1); STAGE_A_(0, 32768, 1);
    asm volatile("s_waitcnt vmcnt(6)" ::: "memory");   // tile 0 resident
    BAR();
    LOAD_BFR(bfrA, 0);           // B frags of tile 0 (even buffer)

    // ---- main loop: tiles 0..13 in even/odd pairs ----
    #pragma unroll 1
    for (int t = 0; t < 7; ++t) {
        TILE_BODY(2 * t,     0,     32768, bfrA, bfrB, 1, "vmcnt(6)");
        TILE_BODY(2 * t + 1, 32768, 0,     bfrB, bfrA, 1, "vmcnt(6)");
    }
    // ---- tail: tiles 14, 15 (stage guards auto-off) ----
    TILE_BODY(14, 0,     32768, bfrA, bfrB, 1, "vmcnt(0)");
    TILE_BODY(15, 32768, 0,     bfrB, bfrA, 0, "vmcnt(0)");

    // ---- epilogue: C/D map col=lane&15, row=(lane>>4)*4+reg ----
    float* outb = out + (size_t)bb * NCH * NFRM;
    #pragma unroll
    for (int MI = 0; MI < 8; ++MI) {
        int g0 = c0 + wr * 128 + MI * 16 + lg * 4;
        #pragma unroll
        for (int ni = 0; ni < 4; ++ni) {
            int f = f0 + wc * 64 + ni * 16 + l16;
            if (f < NFRM) {
                #pragma unroll
                for (int i = 0; i < 4; ++i) {
                    int g = g0 + i;
                    int c = g + (g >= NBINS);   // skip zero channel 513
                    outb[(size_t)c * NFRM + f] = acc[MI][ni][i];
                }
            }
        }
    }
}

extern "C" void kernel_launch(void* const* d_in, const int* in_sizes, int n_in,
                              void* d_out, int out_size, void* d_ws, size_t ws_size,
                              hipStream_t stream) {
    const float* x      = (const float*)d_in[0];
    // d_in[1] = frequency (unused: omega[c] == 2*pi*c/KSZ exactly by setup)
    const float* window = (const float*)d_in[2];

    __hip_bfloat16* basis = (__hip_bfloat16*)d_ws;            // 2 MiB
    __hip_bfloat16* xbf   = (__hip_bfloat16*)((char*)d_ws + (size_t)MROWS * KSZ * 2);
    float* outp = (float*)d_out;

    hipFuncSetAttribute((const void*)stft_gemm_k,
                        hipFuncAttributeMaxDynamicSharedMemorySize, LDS_BYTES);

    build_basis_k<<<(MROWS * KSZ + 255) / 256, 256, 0, stream>>>(window, basis);
    convert_x_k<<<2048, 256, 0, stream>>>(x, xbf);
    zero_rows_k<<<(NBATCH * 2 * NFRM + 255) / 256, 256, 0, stream>>>(outp);

    dim3 grid(2048 / BN, MROWS / BM, NBATCH);   // 8 x 4 x 16 = 512 blocks
    stft_gemm_k<<<grid, 512, LDS_BYTES, stream>>>(basis, xbf, outp);
}